// Round 5
// baseline (292.834 us; speedup 1.0000x reference)
//
#include <hip/hip_runtime.h>

#define KC 1024   // codes
#define DD 128    // dim
#define NT_COUNT (KC / 16)   // 64 code-tiles of 16
#define RPB 64    // rows per block (one wave, 4 m-tiles)

typedef short bf16x8 __attribute__((ext_vector_type(8)));
typedef float f32x4  __attribute__((ext_vector_type(4)));

#define AS1 __attribute__((address_space(1)))
#define AS3 __attribute__((address_space(3)))

static __device__ __forceinline__ unsigned short f2bf(float f) {
    unsigned u = __float_as_uint(f);
    unsigned r = (u + 0x7fffu + ((u >> 16) & 1u)) >> 16;   // RNE
    return (unsigned short)r;
}
static __device__ __forceinline__ float bf2f(unsigned short h) {
    return __uint_as_float(((unsigned)h) << 16);
}
static __device__ __forceinline__ void gl_lds16(const void* g, void* l) {
    __builtin_amdgcn_global_load_lds((const AS1 void*)g, (AS3 void*)l, 16, 0, 0);
}
static __device__ __forceinline__ void gl_lds4(const void* g, void* l) {
    __builtin_amdgcn_global_load_lds((const AS1 void*)g, (AS3 void*)l, 4, 0, 0);
}

// ---------------- fused prep: e2h (+512 offset) + ET + packed bf16 hi/lo B-fragments ----------------
// Bpk byte layout: [nt][c(8)x1024][lane(64)x16]; c<4 = hi s=c, c>=4 = lo s=c-4.
//   element (d,k): d = s*32 + (lane>>4)*8 + j ; k = nt*16 + (lane&15)
__global__ __launch_bounds__(256) void vq_prep(const float* __restrict__ E,
                                               float* __restrict__ e2h,
                                               float* __restrict__ ET,
                                               unsigned short* __restrict__ Bpk) {
    __shared__ float T[16 * 129];   // [k][d]
    const int nt  = blockIdx.x;     // 64 blocks, 16 codes each
    const int tid = threadIdx.x;

    for (int i = tid; i < 16 * DD; i += 256) {
        int d  = i >> 4;
        int kk = i & 15;
        T[kk * 129 + d] = E[(size_t)d * KC + nt * 16 + kk];
    }
    __syncthreads();

    // e2h = 512 - 0.5*||e_k||^2 (offset keeps all screen scores positive)
    if (tid < 16) {
        float s = 0.f;
#pragma unroll 16
        for (int d = 0; d < DD; ++d) {
            float v = T[tid * 129 + d];
            s = fmaf(v, v, s);
        }
        e2h[nt * 16 + tid] = 512.0f - 0.5f * s;
    }

    for (int i = tid; i < 16 * DD; i += 256) {
        int kk = i >> 7;
        int d  = i & 127;
        ET[(size_t)(nt * 16 + kk) * DD + d] = T[kk * 129 + d];
    }

    {
        const int s    = tid >> 6;
        const int lane = tid & 63;
        const int kk   = lane & 15;
        const int d0   = s * 32 + (lane >> 4) * 8;
        bf16x8 hi, lo;
#pragma unroll
        for (int j = 0; j < 8; ++j) {
            float v = T[kk * 129 + d0 + j];
            unsigned short h = f2bf(v);
            hi[j] = (short)h;
            lo[j] = (short)f2bf(v - bf2f(h));
        }
        char* base = (char*)Bpk + (size_t)nt * 8192 + s * 1024 + lane * 16;
        *(bf16x8*)(base)        = hi;
        *(bf16x8*)(base + 4096) = lo;
    }
}

// ---------------- main: single-wave, 64 rows/wave, depth-2 LDS ring + interleaved staging ----------------
// LDS: 3 buffers x 8448 ([c(8)x1024 frags][e2 256B]), ring by nt%3. Tile nt+2's
// 9 loads are issued in groups of 2-3 BETWEEN the 4 MFMA clusters of TILE(nt)
// (sched_barrier-pinned), so loads get ~2 tile-periods to land and VMEM bursts
// shrink from 9 to <=3. vmcnt stays counted (9) until the tail.
__global__ __launch_bounds__(64, 2) void vq_main(const float* __restrict__ X,
                                                 const float* __restrict__ e2h,
                                                 const float* __restrict__ ET,
                                                 const unsigned short* __restrict__ Bpk,
                                                 float* __restrict__ Out) {
    __shared__ __align__(16) char lds[3 * 8448];
    int*   s_k1  = (int*)(lds);          // [64]  (overlay buf0 head, post-loop)
    int*   s_k2  = (int*)(lds + 256);    // [64]
    int*   s_win = (int*)(lds + 512);    // [64]
    float* s_gap = (float*)(lds + 768);  // [64] screen top1-top2 margin

    const int lane  = threadIdx.x;   // single wave
    const int quad  = lane >> 4;
    const int n16   = lane & 15;
    const int wrow0 = blockIdx.x * RPB;
    const int lidx16 = lane * 16;
    const int lidx4  = lane * 4;

    // ---- A-fragments: 4 m-tiles x 4 k-steps, hi+lo (128 VGPRs)
    bf16x8 ahi[4][4], alo[4][4];
#pragma unroll
    for (int t = 0; t < 4; ++t) {
#pragma unroll
        for (int s = 0; s < 4; ++s) {
            const int row = wrow0 + t * 16 + n16;
            const int d0  = s * 32 + quad * 8;
            const float4 p = *(const float4*)(X + (size_t)row * DD + d0);
            const float4 q = *(const float4*)(X + (size_t)row * DD + d0 + 4);
            float v[8] = {p.x, p.y, p.z, p.w, q.x, q.y, q.z, q.w};
#pragma unroll
            for (int j = 0; j < 8; ++j) {
                unsigned short h = f2bf(v[j]);
                ahi[t][s][j] = (short)h;
                alo[t][s][j] = (short)f2bf(v[j] - bf2f(h));
            }
        }
    }

    // ---- top-2 trackers: positive floats with 6-bit tile id in low mantissa bits
    float p1[4][4], p2[4][4];
#pragma unroll
    for (int t = 0; t < 4; ++t)
#pragma unroll
        for (int r = 0; r < 4; ++r) { p1[t][r] = 0.0f; p2[t][r] = 0.0f; }

#define CLUSTER(T)                                                               \
    do {                                                                         \
        f32x4 aA = {ev, ev, ev, ev};                                             \
        f32x4 aB = {0.f, 0.f, 0.f, 0.f};                                         \
        f32x4 aC = {0.f, 0.f, 0.f, 0.f};                                         \
        aA = __builtin_amdgcn_mfma_f32_16x16x32_bf16(ahi[T][0], bh0, aA, 0, 0, 0); \
        aB = __builtin_amdgcn_mfma_f32_16x16x32_bf16(alo[T][0], bh0, aB, 0, 0, 0); \
        aC = __builtin_amdgcn_mfma_f32_16x16x32_bf16(ahi[T][0], bl0, aC, 0, 0, 0); \
        aA = __builtin_amdgcn_mfma_f32_16x16x32_bf16(ahi[T][1], bh1, aA, 0, 0, 0); \
        aB = __builtin_amdgcn_mfma_f32_16x16x32_bf16(alo[T][1], bh1, aB, 0, 0, 0); \
        aC = __builtin_amdgcn_mfma_f32_16x16x32_bf16(ahi[T][1], bl1, aC, 0, 0, 0); \
        aA = __builtin_amdgcn_mfma_f32_16x16x32_bf16(ahi[T][2], bh2, aA, 0, 0, 0); \
        aB = __builtin_amdgcn_mfma_f32_16x16x32_bf16(alo[T][2], bh2, aB, 0, 0, 0); \
        aC = __builtin_amdgcn_mfma_f32_16x16x32_bf16(ahi[T][2], bl2, aC, 0, 0, 0); \
        aA = __builtin_amdgcn_mfma_f32_16x16x32_bf16(ahi[T][3], bh3, aA, 0, 0, 0); \
        aB = __builtin_amdgcn_mfma_f32_16x16x32_bf16(alo[T][3], bh3, aB, 0, 0, 0); \
        aC = __builtin_amdgcn_mfma_f32_16x16x32_bf16(ahi[T][3], bl3, aC, 0, 0, 0); \
        _Pragma("unroll")                                                        \
        for (int r = 0; r < 4; ++r) {                                            \
            float sv = (aA[r] + aB[r]) + aC[r];                                  \
            float v = __uint_as_float((__float_as_uint(sv) & ~63u) | ntinv);     \
            float lo = fminf(p1[T][r], v);                                       \
            p1[T][r] = fmaxf(p1[T][r], v);                                       \
            p2[T][r] = fmaxf(p2[T][r], lo);                                      \
        }                                                                        \
    } while (0)

// BODY(NT, BOFF, SNT, SBOFF, DOSTAGE, WENC):
//   wait WENC; read B-frags of tile NT from buf BOFF; compute 4 clusters while
//   issuing tile SNT's 9 loads into buf SBOFF in groups of <=3 between clusters.
#define BODY(NT, BOFF, SNT, SBOFF, DOSTAGE, WENC)                                \
    do {                                                                         \
        __builtin_amdgcn_s_waitcnt(WENC);                                        \
        __builtin_amdgcn_sched_barrier(0);                                       \
        const char* l = lds + (BOFF);                                            \
        const bf16x8 bh0 = *(const bf16x8*)(l + 0 * 1024 + lidx16);              \
        const bf16x8 bh1 = *(const bf16x8*)(l + 1 * 1024 + lidx16);              \
        const bf16x8 bh2 = *(const bf16x8*)(l + 2 * 1024 + lidx16);              \
        const bf16x8 bh3 = *(const bf16x8*)(l + 3 * 1024 + lidx16);              \
        const bf16x8 bl0 = *(const bf16x8*)(l + 4 * 1024 + lidx16);              \
        const bf16x8 bl1 = *(const bf16x8*)(l + 5 * 1024 + lidx16);              \
        const bf16x8 bl2 = *(const bf16x8*)(l + 6 * 1024 + lidx16);              \
        const bf16x8 bl3 = *(const bf16x8*)(l + 7 * 1024 + lidx16);              \
        const float  ev  = *(const float*)(l + 8192 + lidx4);                    \
        const unsigned ntinv = (unsigned)(63 - (NT));                            \
        const char* g = (const char*)Bpk + (size_t)(SNT) * 8192;                 \
        char* sl = lds + (SBOFF);                                                \
        if (DOSTAGE) {                                                           \
            gl_lds16(g + 0 * 1024 + lidx16, sl + 0 * 1024);                      \
            gl_lds16(g + 1 * 1024 + lidx16, sl + 1 * 1024);                      \
            gl_lds16(g + 2 * 1024 + lidx16, sl + 2 * 1024);                      \
        }                                                                        \
        __builtin_amdgcn_sched_barrier(0);                                       \
        CLUSTER(0);                                                              \
        if (DOSTAGE) {                                                           \
            gl_lds16(g + 3 * 1024 + lidx16, sl + 3 * 1024);                      \
            gl_lds16(g + 4 * 1024 + lidx16, sl + 4 * 1024);                      \
        }                                                                        \
        __builtin_amdgcn_sched_barrier(0);                                       \
        CLUSTER(1);                                                              \
        if (DOSTAGE) {                                                           \
            gl_lds16(g + 5 * 1024 + lidx16, sl + 5 * 1024);                      \
            gl_lds16(g + 6 * 1024 + lidx16, sl + 6 * 1024);                      \
        }                                                                        \
        __builtin_amdgcn_sched_barrier(0);                                       \
        CLUSTER(2);                                                              \
        if (DOSTAGE) {                                                           \
            gl_lds16(g + 7 * 1024 + lidx16, sl + 7 * 1024);                      \
            gl_lds4(e2h + (SNT) * 16 + n16, sl + 8192);                          \
        }                                                                        \
        __builtin_amdgcn_sched_barrier(0);                                       \
        CLUSTER(3);                                                              \
    } while (0)

#define STAGE_ALL(NT, BOFF)                                                      \
    do {                                                                         \
        const char* g = (const char*)Bpk + (size_t)(NT) * 8192;                  \
        _Pragma("unroll")                                                        \
        for (int c = 0; c < 8; ++c)                                              \
            gl_lds16(g + c * 1024 + lidx16, lds + (BOFF) + c * 1024);            \
        gl_lds4(e2h + (NT) * 16 + n16, lds + (BOFF) + 8192);                     \
    } while (0)

    // prologue: tiles 0,1 in flight (18 outstanding)
    STAGE_ALL(0, 0);
    STAGE_ALL(1, 8448);
    // main: unroll x3 for compile-time ring offsets; bodies stage nt+2
    for (int nt = 0; nt < NT_COUNT - 4; nt += 3) {
        BODY(nt,     0,        nt + 2, 16896, 1, 3961);   // vmcnt(9)
        BODY(nt + 1, 8448,     nt + 3, 0,     1, 3961);
        BODY(nt + 2, 16896,    nt + 4, 8448,  1, 3961);
    }
    // tail: nt = 60,61 still stage 62,63; 62,63 compute only
    BODY(60, 0,     62, 16896, 1, 3961);
    BODY(61, 8448,  63, 0,     1, 3961);
    BODY(62, 16896, 0,  0,     0, 3961);   // vmcnt(9): 63's 9 still in flight
    BODY(63, 0,     0,  0,     0, 3952);   // vmcnt(0)
#undef BODY
#undef CLUSTER
#undef STAGE_ALL

    // ---- re-attach full k, merge top-2 across the 16 n-lanes (u64 butterfly)
#pragma unroll
    for (int t = 0; t < 4; ++t) {
#pragma unroll
        for (int r = 0; r < 4; ++r) {
            unsigned u1 = __float_as_uint(p1[t][r]);
            unsigned u2 = __float_as_uint(p2[t][r]);
            int k1 = (int)(63u - (u1 & 63u)) * 16 + n16;
            int k2 = (int)(63u - (u2 & 63u)) * 16 + n16;
            unsigned long long q1 =
                ((unsigned long long)(u1 & ~63u) << 32) | (unsigned)(1023 - k1);
            unsigned long long q2 =
                ((unsigned long long)(u2 & ~63u) << 32) | (unsigned)(1023 - k2);
#pragma unroll
            for (int m = 1; m < 16; m <<= 1) {
                unsigned long long o1 = __shfl_xor(q1, m, 64);
                unsigned long long o2 = __shfl_xor(q2, m, 64);
                unsigned long long lo = q1 < o1 ? q1 : o1;
                q1 = q1 > o1 ? q1 : o1;
                unsigned long long hi2 = q2 > o2 ? q2 : o2;
                q2 = lo > hi2 ? lo : hi2;
            }
            if (n16 == 0) {
                int row = t * 16 + quad * 4 + r;
                s_k1[row] = 1023 - (int)(q1 & 1023u);
                s_k2[row] = 1023 - (int)(q2 & 1023u);
                // screen margin (id bits already cleared in both high words)
                s_gap[row] = __uint_as_float((unsigned)(q1 >> 32)) -
                             __uint_as_float((unsigned)(q2 >> 32));
            }
        }
    }
    __syncthreads();

    // ---- fp64 rescore: ONLY for rows whose screen margin is within the error
    // bound of the bf16 hi/lo screen (~0.06 worst case incl. reassociation;
    // THR=0.5 gives 8x margin, so gap >= THR proves k1 is the exact argmin).
    // Typical gaps are ~4-5, so ~90% of lanes skip the divergent gather.
    {
        const int k1 = s_k1[lane];
        const int k2 = s_k2[lane];
        int win = k1;
        if (s_gap[lane] < 0.5f) {
            const float4* __restrict__ xr  = (const float4*)(X + (size_t)(wrow0 + lane) * DD);
            const float4* __restrict__ e1  = (const float4*)(ET + (size_t)k1 * DD);
            const float4* __restrict__ e2p = (const float4*)(ET + (size_t)k2 * DD);
            double dot1 = 0.0, ee1 = 0.0, dot2 = 0.0, ee2 = 0.0;
#pragma unroll 4
            for (int d4 = 0; d4 < DD / 4; ++d4) {
                const float4 xv = xr[d4];
                const float4 v1 = e1[d4];
                const float4 v2 = e2p[d4];
                const float xs[4] = {xv.x, xv.y, xv.z, xv.w};
                const float a1[4] = {v1.x, v1.y, v1.z, v1.w};
                const float a2[4] = {v2.x, v2.y, v2.z, v2.w};
#pragma unroll
                for (int j = 0; j < 4; ++j) {   // same accumulation order as before
                    const double xd  = (double)xs[j];
                    const double v1d = (double)a1[j];
                    const double v2d = (double)a2[j];
                    dot1 = fma(xd, v1d, dot1);
                    ee1  = fma(v1d, v1d, ee1);
                    dot2 = fma(xd, v2d, dot2);
                    ee2  = fma(v2d, v2d, ee2);
                }
            }
            double d1 = ee1 - 2.0 * dot1;
            double d2 = ee2 - 2.0 * dot2;
            win = (d2 < d1 || (d2 == d1 && k2 < k1)) ? k2 : k1;
        }
        s_win[lane] = win;
    }
    __syncthreads();

    // ---- gather winning code rows (exact fp32 copies), coalesced float4
    for (int i = lane; i < RPB * (DD / 4); i += 64) {
        const int row = i >> 5;
        const int d4  = i & 31;
        const float4 v = *(const float4*)(ET + (size_t)s_win[row] * DD + d4 * 4);
        *(float4*)(Out + (size_t)(wrow0 + row) * DD + d4 * 4) = v;
    }
}

extern "C" void kernel_launch(void* const* d_in, const int* in_sizes, int n_in,
                              void* d_out, int out_size, void* d_ws, size_t ws_size,
                              hipStream_t stream) {
    const float* X = (const float*)d_in[0];   // [131072, 128]
    const float* E = (const float*)d_in[1];   // [128, 1024]
    float* Out = (float*)d_out;

    // workspace: e2h (4 KB) | ET (512 KB) | Bpk (512 KB)
    float* e2h = (float*)d_ws;
    float* ET  = e2h + KC;
    unsigned short* Bpk = (unsigned short*)(ET + (size_t)KC * DD);

    const int N = in_sizes[0] / DD;   // 131072

    hipLaunchKernelGGL(vq_prep, dim3(NT_COUNT), dim3(256), 0, stream, E, e2h, ET, Bpk);
    hipLaunchKernelGGL(vq_main, dim3(N / RPB), dim3(64), 0, stream,
                       X, e2h, ET, Bpk, Out);
}

// Round 6
// 276.443 us; speedup vs baseline: 1.0593x; 1.0593x over previous
//
#include <hip/hip_runtime.h>

#define KC 1024   // codes
#define DD 128    // dim
#define NT_COUNT (KC / 16)   // 64 code-tiles of 16
#define RPB 64    // rows per block (one wave, 4 m-tiles)

typedef short bf16x8 __attribute__((ext_vector_type(8)));
typedef float f32x4  __attribute__((ext_vector_type(4)));

#define AS1 __attribute__((address_space(1)))
#define AS3 __attribute__((address_space(3)))

// s_waitcnt immediates: 0xF70 = expcnt/lgkm no-wait; vmcnt[3:0] in [3:0], vmcnt[5:4] in [15:14]
#define VMC16 20336   // vmcnt(16) = 0x4F70
#define VMC8  3960    // vmcnt(8)
#define VMC0  3952    // vmcnt(0)

static __device__ __forceinline__ unsigned short f2bf(float f) {
    unsigned u = __float_as_uint(f);
    unsigned r = (u + 0x7fffu + ((u >> 16) & 1u)) >> 16;   // RNE
    return (unsigned short)r;
}
static __device__ __forceinline__ float bf2f(unsigned short h) {
    return __uint_as_float(((unsigned)h) << 16);
}
static __device__ __forceinline__ void gl_lds16(const void* g, void* l) {
    __builtin_amdgcn_global_load_lds((const AS1 void*)g, (AS3 void*)l, 16, 0, 0);
}

// ---------------- fused prep: e2h (+512 offset) + ET + packed bf16 hi/lo B-fragments ----------------
// Bpk byte layout: [nt][c(8)x1024][lane(64)x16]; c<4 = hi s=c, c>=4 = lo s=c-4.
//   element (d,k): d = s*32 + (lane>>4)*8 + j ; k = nt*16 + (lane&15)
__global__ __launch_bounds__(256) void vq_prep(const float* __restrict__ E,
                                               float* __restrict__ e2h,
                                               float* __restrict__ ET,
                                               unsigned short* __restrict__ Bpk) {
    __shared__ float T[16 * 129];   // [k][d]
    const int nt  = blockIdx.x;     // 64 blocks, 16 codes each
    const int tid = threadIdx.x;

    for (int i = tid; i < 16 * DD; i += 256) {
        int d  = i >> 4;
        int kk = i & 15;
        T[kk * 129 + d] = E[(size_t)d * KC + nt * 16 + kk];
    }
    __syncthreads();

    // e2h = 512 - 0.5*||e_k||^2 (offset keeps all screen scores positive)
    if (tid < 16) {
        float s = 0.f;
#pragma unroll 16
        for (int d = 0; d < DD; ++d) {
            float v = T[tid * 129 + d];
            s = fmaf(v, v, s);
        }
        e2h[nt * 16 + tid] = 512.0f - 0.5f * s;
    }

    for (int i = tid; i < 16 * DD; i += 256) {
        int kk = i >> 7;
        int d  = i & 127;
        ET[(size_t)(nt * 16 + kk) * DD + d] = T[kk * 129 + d];
    }

    {
        const int s    = tid >> 6;
        const int lane = tid & 63;
        const int kk   = lane & 15;
        const int d0   = s * 32 + (lane >> 4) * 8;
        bf16x8 hi, lo;
#pragma unroll
        for (int j = 0; j < 8; ++j) {
            float v = T[kk * 129 + d0 + j];
            unsigned short h = f2bf(v);
            hi[j] = (short)h;
            lo[j] = (short)f2bf(v - bf2f(h));
        }
        char* base = (char*)Bpk + (size_t)nt * 8192 + s * 1024 + lane * 16;
        *(bf16x8*)(base)        = hi;
        *(bf16x8*)(base + 4096) = lo;
    }
}

// ---------------- main: single-wave, 64 rows/wave, DEPTH-2 burst prefetch ----------------
// LDS: 3 tile buffers x 8192 (ring T%3) + e2h[1024] static (4KB). Tiles T,T+1
// always in flight; per body: burst-stage T+2 (8x gl_lds16), vmcnt(16) waits
// ONLY tile T's 8 loads (2 full tile-periods to land), then compute tile T.
// setprio(1) wraps the MFMA clusters (waves drift out of phase; T5).
__global__ __launch_bounds__(64, 2) void vq_main(const float* __restrict__ X,
                                                 const float* __restrict__ e2h,
                                                 const float* __restrict__ ET,
                                                 const unsigned short* __restrict__ Bpk,
                                                 float* __restrict__ Out) {
    __shared__ __align__(16) char lds[3 * 8192 + 4096];
    float* s_e2  = (float*)(lds + 24576);   // [1024] e2h, static
    int*   s_k1  = (int*)(lds);             // [64]  (overlay buf0, post-loop)
    int*   s_k2  = (int*)(lds + 256);       // [64]
    int*   s_win = (int*)(lds + 512);       // [64]
    float* s_gap = (float*)(lds + 768);     // [64] screen top1-top2 margin

    const int lane  = threadIdx.x;   // single wave
    const int quad  = lane >> 4;
    const int n16   = lane & 15;
    const int wrow0 = blockIdx.x * RPB;
    const int lidx16 = lane * 16;

    // ---- A-fragments: 4 m-tiles x 4 k-steps, hi+lo (128 VGPRs)
    bf16x8 ahi[4][4], alo[4][4];
#pragma unroll
    for (int t = 0; t < 4; ++t) {
#pragma unroll
        for (int s = 0; s < 4; ++s) {
            const int row = wrow0 + t * 16 + n16;
            const int d0  = s * 32 + quad * 8;
            const float4 p = *(const float4*)(X + (size_t)row * DD + d0);
            const float4 q = *(const float4*)(X + (size_t)row * DD + d0 + 4);
            float v[8] = {p.x, p.y, p.z, p.w, q.x, q.y, q.z, q.w};
#pragma unroll
            for (int j = 0; j < 8; ++j) {
                unsigned short h = f2bf(v[j]);
                ahi[t][s][j] = (short)h;
                alo[t][s][j] = (short)f2bf(v[j] - bf2f(h));
            }
        }
    }

    // ---- e2h preload into static LDS (once); consumes its loads (vmcnt clean)
    for (int i = lane; i < KC; i += 64) s_e2[i] = e2h[i];
    __syncthreads();   // single wave: drains vmcnt/lgkm before staging begins

    // ---- top-2 trackers: positive floats with 6-bit tile id in low mantissa bits
    float p1[4][4], p2[4][4];
#pragma unroll
    for (int t = 0; t < 4; ++t)
#pragma unroll
        for (int r = 0; r < 4; ++r) { p1[t][r] = 0.0f; p2[t][r] = 0.0f; }

#define STAGE(T, BOFF)                                                           \
    do {                                                                         \
        const char* g = (const char*)Bpk + (size_t)(T) * 8192;                   \
        _Pragma("unroll")                                                        \
        for (int c = 0; c < 8; ++c)                                              \
            gl_lds16(g + c * 1024 + lidx16, lds + (BOFF) + c * 1024);            \
    } while (0)

// BODY(T, BOFF, STG, SBOFF, WENC): burst-stage tile T+2 into SBOFF (if STG),
// wait WENC (counted), compute tile T from BOFF.
#define BODY(T, BOFF, STG, SBOFF, WENC)                                          \
    do {                                                                         \
        if (STG) STAGE((T) + 2, SBOFF);                                          \
        __builtin_amdgcn_s_waitcnt(WENC);                                        \
        __builtin_amdgcn_sched_barrier(0);                                       \
        const char* l = lds + (BOFF);                                            \
        const bf16x8 bh0 = *(const bf16x8*)(l + 0 * 1024 + lidx16);              \
        const bf16x8 bh1 = *(const bf16x8*)(l + 1 * 1024 + lidx16);              \
        const bf16x8 bh2 = *(const bf16x8*)(l + 2 * 1024 + lidx16);              \
        const bf16x8 bh3 = *(const bf16x8*)(l + 3 * 1024 + lidx16);              \
        const bf16x8 bl0 = *(const bf16x8*)(l + 4 * 1024 + lidx16);              \
        const bf16x8 bl1 = *(const bf16x8*)(l + 5 * 1024 + lidx16);              \
        const bf16x8 bl2 = *(const bf16x8*)(l + 6 * 1024 + lidx16);              \
        const bf16x8 bl3 = *(const bf16x8*)(l + 7 * 1024 + lidx16);              \
        const float  ev  = s_e2[(T) * 16 + n16];                                 \
        const unsigned ntinv = (unsigned)(63 - (T));                             \
        __builtin_amdgcn_s_setprio(1);                                           \
        _Pragma("unroll")                                                        \
        for (int t = 0; t < 4; ++t) {                                            \
            f32x4 aA = {ev, ev, ev, ev};                                         \
            f32x4 aB = {0.f, 0.f, 0.f, 0.f};                                     \
            f32x4 aC = {0.f, 0.f, 0.f, 0.f};                                     \
            aA = __builtin_amdgcn_mfma_f32_16x16x32_bf16(ahi[t][0], bh0, aA, 0, 0, 0); \
            aB = __builtin_amdgcn_mfma_f32_16x16x32_bf16(alo[t][0], bh0, aB, 0, 0, 0); \
            aC = __builtin_amdgcn_mfma_f32_16x16x32_bf16(ahi[t][0], bl0, aC, 0, 0, 0); \
            aA = __builtin_amdgcn_mfma_f32_16x16x32_bf16(ahi[t][1], bh1, aA, 0, 0, 0); \
            aB = __builtin_amdgcn_mfma_f32_16x16x32_bf16(alo[t][1], bh1, aB, 0, 0, 0); \
            aC = __builtin_amdgcn_mfma_f32_16x16x32_bf16(ahi[t][1], bl1, aC, 0, 0, 0); \
            aA = __builtin_amdgcn_mfma_f32_16x16x32_bf16(ahi[t][2], bh2, aA, 0, 0, 0); \
            aB = __builtin_amdgcn_mfma_f32_16x16x32_bf16(alo[t][2], bh2, aB, 0, 0, 0); \
            aC = __builtin_amdgcn_mfma_f32_16x16x32_bf16(ahi[t][2], bl2, aC, 0, 0, 0); \
            aA = __builtin_amdgcn_mfma_f32_16x16x32_bf16(ahi[t][3], bh3, aA, 0, 0, 0); \
            aB = __builtin_amdgcn_mfma_f32_16x16x32_bf16(alo[t][3], bh3, aB, 0, 0, 0); \
            aC = __builtin_amdgcn_mfma_f32_16x16x32_bf16(ahi[t][3], bl3, aC, 0, 0, 0); \
            _Pragma("unroll")                                                    \
            for (int r = 0; r < 4; ++r) {                                        \
                float sv = (aA[r] + aB[r]) + aC[r];                              \
                float v = __uint_as_float((__float_as_uint(sv) & ~63u) | ntinv); \
                float lo = fminf(p1[t][r], v);                                   \
                p1[t][r] = fmaxf(p1[t][r], v);                                   \
                p2[t][r] = fmaxf(p2[t][r], lo);                                  \
            }                                                                    \
        }                                                                        \
        __builtin_amdgcn_s_setprio(0);                                           \
    } while (0)

    // prologue: tiles 0 (b0), 1 (b1) in flight -> 16 outstanding
    STAGE(0, 0);
    STAGE(1, 8192);
    // steady state: before BODY(T), tiles T,T+1 in flight (16). BODY stages
    // T+2 (->24), vmcnt(16) retires exactly tile T's 8 (issued 2 periods ago).
    for (int nt = 0; nt < 60; nt += 3) {
        BODY(nt,     0,     1, 16384, VMC16);   // stages nt+2 -> b2
        BODY(nt + 1, 8192,  1, 0,     VMC16);   // stages nt+3 -> b0
        BODY(nt + 2, 16384, 1, 8192,  VMC16);   // stages nt+4 -> b1
    }
    BODY(60, 0,     1, 16384, VMC16);   // stages 62 -> b2
    BODY(61, 8192,  1, 0,     VMC16);   // stages 63 -> b0
    BODY(62, 16384, 0, 0,     VMC8);    // wait tile 62's 8
    BODY(63, 0,     0, 0,     VMC0);
#undef BODY
#undef STAGE

    // ---- re-attach full k, merge top-2 across the 16 n-lanes (u64 butterfly)
#pragma unroll
    for (int t = 0; t < 4; ++t) {
#pragma unroll
        for (int r = 0; r < 4; ++r) {
            unsigned u1 = __float_as_uint(p1[t][r]);
            unsigned u2 = __float_as_uint(p2[t][r]);
            int k1 = (int)(63u - (u1 & 63u)) * 16 + n16;
            int k2 = (int)(63u - (u2 & 63u)) * 16 + n16;
            unsigned long long q1 =
                ((unsigned long long)(u1 & ~63u) << 32) | (unsigned)(1023 - k1);
            unsigned long long q2 =
                ((unsigned long long)(u2 & ~63u) << 32) | (unsigned)(1023 - k2);
#pragma unroll
            for (int m = 1; m < 16; m <<= 1) {
                unsigned long long o1 = __shfl_xor(q1, m, 64);
                unsigned long long o2 = __shfl_xor(q2, m, 64);
                unsigned long long lo = q1 < o1 ? q1 : o1;
                q1 = q1 > o1 ? q1 : o1;
                unsigned long long hi2 = q2 > o2 ? q2 : o2;
                q2 = lo > hi2 ? lo : hi2;
            }
            if (n16 == 0) {
                int row = t * 16 + quad * 4 + r;
                s_k1[row] = 1023 - (int)(q1 & 1023u);
                s_k2[row] = 1023 - (int)(q2 & 1023u);
                // screen margin (id bits already cleared in both high words)
                s_gap[row] = __uint_as_float((unsigned)(q1 >> 32)) -
                             __uint_as_float((unsigned)(q2 >> 32));
            }
        }
    }
    __syncthreads();

    // ---- fp64 rescore: ONLY for rows whose screen margin is within the error
    // bound of the bf16 hi/lo screen (~0.06 worst case incl. reassociation;
    // THR=0.5 gives 8x margin, so gap >= THR proves k1 is the exact argmin).
    // Typical gaps are ~4-5, so ~90% of lanes skip the divergent gather.
    {
        const int k1 = s_k1[lane];
        const int k2 = s_k2[lane];
        int win = k1;
        if (s_gap[lane] < 0.5f) {
            const float4* __restrict__ xr  = (const float4*)(X + (size_t)(wrow0 + lane) * DD);
            const float4* __restrict__ e1  = (const float4*)(ET + (size_t)k1 * DD);
            const float4* __restrict__ e2p = (const float4*)(ET + (size_t)k2 * DD);
            double dot1 = 0.0, ee1 = 0.0, dot2 = 0.0, ee2 = 0.0;
#pragma unroll 4
            for (int d4 = 0; d4 < DD / 4; ++d4) {
                const float4 xv = xr[d4];
                const float4 v1 = e1[d4];
                const float4 v2 = e2p[d4];
                const float xs[4] = {xv.x, xv.y, xv.z, xv.w};
                const float a1[4] = {v1.x, v1.y, v1.z, v1.w};
                const float a2[4] = {v2.x, v2.y, v2.z, v2.w};
#pragma unroll
                for (int j = 0; j < 4; ++j) {   // same accumulation order as before
                    const double xd  = (double)xs[j];
                    const double v1d = (double)a1[j];
                    const double v2d = (double)a2[j];
                    dot1 = fma(xd, v1d, dot1);
                    ee1  = fma(v1d, v1d, ee1);
                    dot2 = fma(xd, v2d, dot2);
                    ee2  = fma(v2d, v2d, ee2);
                }
            }
            double d1 = ee1 - 2.0 * dot1;
            double d2 = ee2 - 2.0 * dot2;
            win = (d2 < d1 || (d2 == d1 && k2 < k1)) ? k2 : k1;
        }
        s_win[lane] = win;
    }
    __syncthreads();

    // ---- gather winning code rows (exact fp32 copies), coalesced float4
    for (int i = lane; i < RPB * (DD / 4); i += 64) {
        const int row = i >> 5;
        const int d4  = i & 31;
        const float4 v = *(const float4*)(ET + (size_t)s_win[row] * DD + d4 * 4);
        *(float4*)(Out + (size_t)(wrow0 + row) * DD + d4 * 4) = v;
    }
}

extern "C" void kernel_launch(void* const* d_in, const int* in_sizes, int n_in,
                              void* d_out, int out_size, void* d_ws, size_t ws_size,
                              hipStream_t stream) {
    const float* X = (const float*)d_in[0];   // [131072, 128]
    const float* E = (const float*)d_in[1];   // [128, 1024]
    float* Out = (float*)d_out;

    // workspace: e2h (4 KB) | ET (512 KB) | Bpk (512 KB)
    float* e2h = (float*)d_ws;
    float* ET  = e2h + KC;
    unsigned short* Bpk = (unsigned short*)(ET + (size_t)KC * DD);

    const int N = in_sizes[0] / DD;   // 131072

    hipLaunchKernelGGL(vq_prep, dim3(NT_COUNT), dim3(256), 0, stream, E, e2h, ET, Bpk);
    hipLaunchKernelGGL(vq_main, dim3(N / RPB), dim3(64), 0, stream,
                       X, e2h, ET, Bpk, Out);
}

// Round 7
// 242.523 us; speedup vs baseline: 1.2074x; 1.1399x over previous
//
#include <hip/hip_runtime.h>

#define KC 1024   // codes
#define DD 128    // dim
#define NT32 32   // 32 code-tiles of 32
#define RPB 64    // rows per block (one wave, 2 m-tiles of 32)

typedef short bf16x8  __attribute__((ext_vector_type(8)));
typedef float f32x16  __attribute__((ext_vector_type(16)));

#define AS1 __attribute__((address_space(1)))
#define AS3 __attribute__((address_space(3)))

#define VMC8 3960   // s_waitcnt vmcnt(8), lgkm/exp no-wait
#define VMC0 3952   // s_waitcnt vmcnt(0)

static __device__ __forceinline__ unsigned short f2bf(float f) {
    unsigned u = __float_as_uint(f);
    unsigned r = (u + 0x7fffu + ((u >> 16) & 1u)) >> 16;   // RNE
    return (unsigned short)r;
}
static __device__ __forceinline__ float bf2f(unsigned short h) {
    return __uint_as_float(((unsigned)h) << 16);
}
static __device__ __forceinline__ void gl_lds16(const void* g, void* l) {
    __builtin_amdgcn_global_load_lds((const AS1 void*)g, (AS3 void*)l, 16, 0, 0);
}

// ---------------- fused prep: e2h (+512 offset) + ET + packed bf16 hi/lo B-fragments ----------------
// Bpk byte layout (32x32x16 B-frags): tile nt (32 codes), k-step s (0..7):
//   byte base = nt*16384 + (s>>2)*8192 + (s&3)*2048 + lane*16; hi at +0, lo at +1024.
//   element (k, code): code = nt*32 + (lane&31), k = s*16 + (lane>>5)*8 + j, j=0..7
__global__ __launch_bounds__(256) void vq_prep(const float* __restrict__ E,
                                               float* __restrict__ e2h,
                                               float* __restrict__ ET,
                                               unsigned short* __restrict__ Bpk) {
    __shared__ float T[32 * 129];   // [code][d]
    const int nt  = blockIdx.x;     // 32 blocks, 32 codes each
    const int tid = threadIdx.x;

    for (int i = tid; i < 32 * DD; i += 256) {
        int d  = i >> 5;
        int kk = i & 31;
        T[kk * 129 + d] = E[(size_t)d * KC + nt * 32 + kk];
    }
    __syncthreads();

    // e2h = 512 - 0.5*||e_k||^2 (offset keeps all screen scores positive)
    if (tid < 32) {
        float s = 0.f;
#pragma unroll 16
        for (int d = 0; d < DD; ++d) {
            float v = T[tid * 129 + d];
            s = fmaf(v, v, s);
        }
        e2h[nt * 32 + tid] = 512.0f - 0.5f * s;
    }

    for (int i = tid; i < 32 * DD; i += 256) {
        int kk = i >> 7;
        int d  = i & 127;
        ET[(size_t)(nt * 32 + kk) * DD + d] = T[kk * 129 + d];
    }

    // pack B-frags: 8 s-steps x 64 lanes; 256 threads -> 2 iterations
#pragma unroll
    for (int it = 0; it < 2; ++it) {
        const int s    = (tid >> 6) + 4 * it;
        const int lane = tid & 63;
        const int code = lane & 31;
        const int kb   = s * 16 + (lane >> 5) * 8;
        bf16x8 hi, lo;
#pragma unroll
        for (int j = 0; j < 8; ++j) {
            float v = T[code * 129 + kb + j];
            unsigned short h = f2bf(v);
            hi[j] = (short)h;
            lo[j] = (short)f2bf(v - bf2f(h));
        }
        char* base = (char*)Bpk + (size_t)nt * 16384 + (s >> 2) * 8192 + (s & 3) * 2048 + lane * 16;
        *(bf16x8*)(base)        = hi;
        *(bf16x8*)(base + 1024) = lo;
    }
}

// ---------------- main: single-wave, 64 rows/wave, 32x32x16 MFMA, 2-buffer half-tile ring ----------------
// Screen: 3-pass hi/lo bf16 limbs, chained through the MFMA C operand (R4 proved
// chains cost-free), acc init = e2h. Half the MFMA instructions of the 16x16 form
// (1536/wave) at a higher per-inst rate: attacks the per-wave issue-serial floor.
// LDS: 2 x 8192 half-tile buffers + 4KB static e2h = 20480 B -> exactly 8 blocks/CU.
__global__ __launch_bounds__(64, 2) void vq_main(const float* __restrict__ X,
                                                 const float* __restrict__ e2h,
                                                 const float* __restrict__ ET,
                                                 const unsigned short* __restrict__ Bpk,
                                                 float* __restrict__ Out) {
    __shared__ __align__(16) char lds[2 * 8192];
    __shared__ float s_e2[KC];
    int*   s_k1  = (int*)(lds);          // [64]  (overlay buf0, post-loop)
    int*   s_k2  = (int*)(lds + 256);    // [64]
    int*   s_win = (int*)(lds + 512);    // [64]
    float* s_gap = (float*)(lds + 768);  // [64] screen top1-top2 margin

    const int lane  = threadIdx.x;   // single wave
    const int l31   = lane & 31;
    const int khalf = lane >> 5;     // 0/1
    const int wrow0 = blockIdx.x * RPB;
    const int lidx16 = lane * 16;

    // ---- A-fragments: 2 m-tiles x 8 k-steps, hi+lo (128 VGPRs)
    // layout: row = m*32 + (lane&31), k = s*16 + (lane>>5)*8 + j
    bf16x8 ahi[2][8], alo[2][8];
#pragma unroll
    for (int m = 0; m < 2; ++m) {
#pragma unroll
        for (int s = 0; s < 8; ++s) {
            const int row = wrow0 + m * 32 + l31;
            const int d0  = s * 16 + khalf * 8;
            const float4 p = *(const float4*)(X + (size_t)row * DD + d0);
            const float4 q = *(const float4*)(X + (size_t)row * DD + d0 + 4);
            float v[8] = {p.x, p.y, p.z, p.w, q.x, q.y, q.z, q.w};
#pragma unroll
            for (int j = 0; j < 8; ++j) {
                unsigned short h = f2bf(v[j]);
                ahi[m][s][j] = (short)h;
                alo[m][s][j] = (short)f2bf(v[j] - bf2f(h));
            }
        }
    }

    // ---- e2h preload into static LDS (once); syncthreads drains vm/lgkm
    for (int i = lane; i < KC; i += 64) s_e2[i] = e2h[i];
    __syncthreads();

    // ---- top-2 trackers: positive floats with 5-bit tile id in low mantissa bits
    float p1[2][16], p2[2][16];
#pragma unroll
    for (int m = 0; m < 2; ++m)
#pragma unroll
        for (int r = 0; r < 16; ++r) { p1[m][r] = 0.0f; p2[m][r] = 0.0f; }

    // half-tile h (0..63) lives at Bpk + h*8192; even h -> buf0, odd h -> buf1
#define STAGE(H, BOFF)                                                           \
    do {                                                                         \
        const char* g = (const char*)Bpk + (size_t)(H) * 8192;                   \
        _Pragma("unroll")                                                        \
        for (int c = 0; c < 8; ++c)                                              \
            gl_lds16(g + c * 1024 + lidx16, lds + (BOFF) + c * 1024);            \
    } while (0)

#define MM(acc, af, bf) acc = __builtin_amdgcn_mfma_f32_32x32x16_bf16(af, bf, acc, 0, 0, 0)

    // 24 MFMA on buffer BOFF, k-steps hf*4..hf*4+3, chained into accA/accB
#define HALF(BOFF, HF)                                                           \
    do {                                                                         \
        const char* l = lds + (BOFF);                                            \
        _Pragma("unroll")                                                        \
        for (int sl = 0; sl < 4; ++sl) {                                         \
            const bf16x8 bh = *(const bf16x8*)(l + sl * 2048 + lidx16);          \
            const bf16x8 bl = *(const bf16x8*)(l + sl * 2048 + 1024 + lidx16);   \
            const int sg = (HF) * 4 + sl;                                        \
            MM(accA, ahi[0][sg], bh);                                            \
            MM(accB, ahi[1][sg], bh);                                            \
            MM(accA, alo[0][sg], bh);                                            \
            MM(accB, alo[1][sg], bh);                                            \
            MM(accA, ahi[0][sg], bl);                                            \
            MM(accB, ahi[1][sg], bl);                                            \
        }                                                                        \
    } while (0)

    STAGE(0, 0);
    for (int h = 0; h < 64; h += 2) {
        const int nt = h >> 1;
        const float ev = s_e2[nt * 32 + l31];   // per-lane code norm term
        f32x16 accA, accB;
#pragma unroll
        for (int r = 0; r < 16; ++r) { accA[r] = ev; accB[r] = ev; }

        STAGE(h + 1, 8192);
        __builtin_amdgcn_s_waitcnt(VMC8);       // half h's 8 complete
        __builtin_amdgcn_sched_barrier(0);
        HALF(0, 0);
        if (h + 2 < 64) {
            STAGE(h + 2, 0);
            __builtin_amdgcn_s_waitcnt(VMC8);   // half h+1's 8 complete
        } else {
            __builtin_amdgcn_s_waitcnt(VMC0);
        }
        __builtin_amdgcn_sched_barrier(0);
        HALF(8192, 1);

        // tracker: mask 5-bit tile id into mantissa, keep top-2 per slot
        const unsigned ntinv = (unsigned)(31 - nt);
#pragma unroll
        for (int m = 0; m < 2; ++m)
#pragma unroll
            for (int r = 0; r < 16; ++r) {
                float sv = (m == 0) ? accA[r] : accB[r];
                float v = __uint_as_float((__float_as_uint(sv) & ~31u) | ntinv);
                float lo = fminf(p1[m][r], v);
                p1[m][r] = fmaxf(p1[m][r], v);
                p2[m][r] = fmaxf(p2[m][r], lo);
            }
    }
#undef HALF
#undef MM
#undef STAGE

    // ---- re-attach full k, merge top-2 across the 32 code-lanes (u64 butterfly)
    // C layout: col(code) = lane&31, row = (r&3) + 8*(r>>2) + 4*(lane>>5)
#pragma unroll
    for (int m = 0; m < 2; ++m) {
#pragma unroll
        for (int r = 0; r < 16; ++r) {
            unsigned u1 = __float_as_uint(p1[m][r]);
            unsigned u2 = __float_as_uint(p2[m][r]);
            int k1 = (int)(31u - (u1 & 31u)) * 32 + l31;
            int k2 = (int)(31u - (u2 & 31u)) * 32 + l31;
            unsigned long long q1 =
                ((unsigned long long)(u1 & ~31u) << 32) | (unsigned)(1023 - k1);
            unsigned long long q2 =
                ((unsigned long long)(u2 & ~31u) << 32) | (unsigned)(1023 - k2);
#pragma unroll
            for (int mm = 1; mm < 32; mm <<= 1) {
                unsigned long long o1 = __shfl_xor(q1, mm, 64);
                unsigned long long o2 = __shfl_xor(q2, mm, 64);
                unsigned long long lo = q1 < o1 ? q1 : o1;
                q1 = q1 > o1 ? q1 : o1;
                unsigned long long hi2 = q2 > o2 ? q2 : o2;
                q2 = lo > hi2 ? lo : hi2;
            }
            if (l31 == 0) {
                int row = m * 32 + (r & 3) + 8 * (r >> 2) + 4 * khalf;
                s_k1[row] = 1023 - (int)(q1 & 1023u);
                s_k2[row] = 1023 - (int)(q2 & 1023u);
                // screen margin (id bits already cleared in both high words)
                s_gap[row] = __uint_as_float((unsigned)(q1 >> 32)) -
                             __uint_as_float((unsigned)(q2 >> 32));
            }
        }
    }
    __syncthreads();

    // ---- fp64 rescore: ONLY for rows whose screen margin is within the error
    // bound of the bf16 hi/lo screen (~0.06 worst case; THR=0.5 gives 8x margin,
    // so gap >= THR proves k1 is the exact argmin). ~90% of lanes skip.
    {
        const int k1 = s_k1[lane];
        const int k2 = s_k2[lane];
        int win = k1;
        if (s_gap[lane] < 0.5f) {
            const float4* __restrict__ xr  = (const float4*)(X + (size_t)(wrow0 + lane) * DD);
            const float4* __restrict__ e1  = (const float4*)(ET + (size_t)k1 * DD);
            const float4* __restrict__ e2p = (const float4*)(ET + (size_t)k2 * DD);
            double dot1 = 0.0, ee1 = 0.0, dot2 = 0.0, ee2 = 0.0;
#pragma unroll 4
            for (int d4 = 0; d4 < DD / 4; ++d4) {
                const float4 xv = xr[d4];
                const float4 v1 = e1[d4];
                const float4 v2 = e2p[d4];
                const float xs[4] = {xv.x, xv.y, xv.z, xv.w};
                const float a1[4] = {v1.x, v1.y, v1.z, v1.w};
                const float a2[4] = {v2.x, v2.y, v2.z, v2.w};
#pragma unroll
                for (int j = 0; j < 4; ++j) {   // same accumulation order as before
                    const double xd  = (double)xs[j];
                    const double v1d = (double)a1[j];
                    const double v2d = (double)a2[j];
                    dot1 = fma(xd, v1d, dot1);
                    ee1  = fma(v1d, v1d, ee1);
                    dot2 = fma(xd, v2d, dot2);
                    ee2  = fma(v2d, v2d, ee2);
                }
            }
            double d1 = ee1 - 2.0 * dot1;
            double d2 = ee2 - 2.0 * dot2;
            win = (d2 < d1 || (d2 == d1 && k2 < k1)) ? k2 : k1;
        }
        s_win[lane] = win;
    }
    __syncthreads();

    // ---- gather winning code rows (exact fp32 copies), coalesced float4
    for (int i = lane; i < RPB * (DD / 4); i += 64) {
        const int row = i >> 5;
        const int d4  = i & 31;
        const float4 v = *(const float4*)(ET + (size_t)s_win[row] * DD + d4 * 4);
        *(float4*)(Out + (size_t)(wrow0 + row) * DD + d4 * 4) = v;
    }
}

extern "C" void kernel_launch(void* const* d_in, const int* in_sizes, int n_in,
                              void* d_out, int out_size, void* d_ws, size_t ws_size,
                              hipStream_t stream) {
    const float* X = (const float*)d_in[0];   // [131072, 128]
    const float* E = (const float*)d_in[1];   // [128, 1024]
    float* Out = (float*)d_out;

    // workspace: e2h (4 KB) | ET (512 KB) | Bpk (512 KB)
    float* e2h = (float*)d_ws;
    float* ET  = e2h + KC;
    unsigned short* Bpk = (unsigned short*)(ET + (size_t)KC * DD);

    const int N = in_sizes[0] / DD;   // 131072

    hipLaunchKernelGGL(vq_prep, dim3(NT32), dim3(256), 0, stream, E, e2h, ET, Bpk);
    hipLaunchKernelGGL(vq_main, dim3(N / RPB), dim3(64), 0, stream,
                       X, e2h, ET, Bpk, Out);
}